// Round 10
// baseline (2295.878 us; speedup 1.0000x reference)
//
#include <hip/hip_runtime.h>
#include <math.h>

typedef __attribute__((ext_vector_type(8))) short short8;
typedef __attribute__((ext_vector_type(4))) float float4v;
typedef __attribute__((ext_vector_type(8))) int int8v;
typedef unsigned short ushort_t;
typedef unsigned char uchar_t;

#define S_LEN 512
#define BATCH 128
#define DMODEL 512
#define HIDDEN 256
#define NTAGS 32
#define MROWS (S_LEN*BATCH)
#define CHUNK 64                  // sequence steps per pre-band (double-buffered)
#define NCH (S_LEN/CHUNK)         // 8 chunks
#define EMB_SCALE 22.62741699796952f

__device__ __forceinline__ float bf2f(ushort_t u){
  union { unsigned int i; float f; } v; v.i = ((unsigned int)u)<<16; return v.f;
}
__device__ __forceinline__ ushort_t f2bf(float f){
  union { float f; unsigned int i; } v; v.f = f;
  unsigned int x = v.i;
  x += 0x7fffu + ((x>>16)&1u);
  return (ushort_t)(x>>16);
}
// float -> OCP e4m3fn, RNE, saturate to 448
__device__ __forceinline__ uchar_t f2fp8(float f){
  float a = fabsf(f);
  unsigned int s = (__float_as_uint(f) >> 24) & 0x80u;
  if (a >= 448.f) return (uchar_t)(s | 0x7Eu);
  if (a < 0.015625f){                         // subnormal: m = round(a*512)
    unsigned int q = (unsigned int)__float2int_rn(a * 512.0f);
    return (uchar_t)(s | q);
  }
  unsigned int x = __float_as_uint(a);
  x += 0x7FFFFu + ((x >> 20) & 1u);           // RNE into 3-bit mantissa
  int e = (int)((x >> 23) & 0xFFu) - 127;
  unsigned int m = (x >> 20) & 7u;
  if (e > 8) return (uchar_t)(s | 0x7Eu);
  return (uchar_t)(s | ((unsigned)(e + 7) << 3) | m);
}
__device__ __forceinline__ float sigm(float x){ return 1.0f/(1.0f+__expf(-x)); }
__device__ __forceinline__ float tanh_f(float x){ return 2.0f/(1.0f+__expf(-2.0f*x)) - 1.0f; }

#define MFMA(a,b,c) __builtin_amdgcn_mfma_f32_16x16x32_bf16(a,b,c,0,0,0)
// block-scaled MX fp8 MFMA, K=128, unit scales (e8m0 0x7F = 2^0)
#define MFMAMX(a,b,c) __builtin_amdgcn_mfma_scale_f32_16x16x128_f8f6f4( \
    a, b, c, 0, 0, 0, 0x7F7F7F7F, 0, 0x7F7F7F7F)

// direct global->LDS 16B copy: wave-uniform LDS base + lane*16; global per-lane
typedef const __attribute__((address_space(1))) void gas_void;
typedef __attribute__((address_space(3))) void las_void;
__device__ __forceinline__ void gload16(const void* g, void* l){
  __builtin_amdgcn_global_load_lds((gas_void*)g, (las_void*)l, 16, 0, 0);
}

// ---------------- elementwise helpers ----------------
__global__ void k_cvt_bf16(const float* __restrict__ s, ushort_t* __restrict__ d, int n){
  int i = blockIdx.x*blockDim.x + threadIdx.x;
  if(i<n) d[i] = f2bf(s[i]);
}
// Whh fp8 quant with k-permutation: pos q holds unit u = 32*(q>>5)+16*(q&1)+((q>>1)&15)
__global__ void k_cvt_fp8p(const float* __restrict__ s, uchar_t* __restrict__ d, int n){
  int i = blockIdx.x*blockDim.x + threadIdx.x;
  if(i<n){
    int row = i >> 8, q = i & 255;
    int u = ((q >> 5) << 5) + ((q & 1) << 4) + ((q >> 1) & 15);
    d[i] = f2fp8(s[row*256 + u]);
  }
}
__global__ void k_biassum(const float* __restrict__ a, const float* __restrict__ b,
                          float* __restrict__ o, int n){
  int i = blockIdx.x*blockDim.x + threadIdx.x;
  if(i<n) o[i] = a[i]+b[i];
}

// ---------------- embedding: x[s,b,:] = emb[src[s,b],:]*sqrt(D)  (bf16 out) ----
__global__ __launch_bounds__(64) void k_embed(const int* __restrict__ src,
                                              const float* __restrict__ emb,
                                              ushort_t* __restrict__ x){
  int row = blockIdx.x;            // 0..65535  (= s*BATCH+b)
  int t = threadIdx.x;             // 64 threads, 8 elems each
  int tok = src[row];
  const float4v* e = (const float4v*)(emb + (size_t)tok*DMODEL + t*8);
  float4v a = e[0], b = e[1];
  short8 o;
  o[0]=(short)f2bf(a[0]*EMB_SCALE); o[1]=(short)f2bf(a[1]*EMB_SCALE);
  o[2]=(short)f2bf(a[2]*EMB_SCALE); o[3]=(short)f2bf(a[3]*EMB_SCALE);
  o[4]=(short)f2bf(b[0]*EMB_SCALE); o[5]=(short)f2bf(b[1]*EMB_SCALE);
  o[6]=(short)f2bf(b[2]*EMB_SCALE); o[7]=(short)f2bf(b[3]*EMB_SCALE);
  *(short8*)(x + (size_t)row*DMODEL + t*8) = o;
}

// ---------------- standalone band pre-GEMM (layer prologue), 256 thr ----------
// 128x128 tile, gate-blocked N (tu): output cols colp in [tu*128,+128)
// contiguous; epilogue repacks via LDS, stores coalesced. dir = blockIdx.z.
__global__ __launch_bounds__(256) void k_gemm_band(
    const ushort_t* __restrict__ xin, int t0,
    const ushort_t* __restrict__ WihL,   // [2,1024,512] bf16
    const float* __restrict__ bsumL,     // [2,1024]
    ushort_t* __restrict__ outF,         // [CHUNK*B,1024] dir0
    ushort_t* __restrict__ outB){        // dir1
  __shared__ __align__(16) uchar_t smem[32768];
  uchar_t* As = smem;
  uchar_t* Bs = smem + 16384;
  int tid = threadIdx.x;
  int tu = blockIdx.x;                  // 0..7
  int bm = blockIdx.y;                  // 0..CHUNK*BATCH/128-1
  int dir = blockIdx.z;
  const uchar_t* Ab = (const uchar_t*)(xin +
      (size_t)(dir ? (S_LEN - t0 - CHUNK) : t0)*BATCH*DMODEL +
      (size_t)bm*128*DMODEL);
  const uchar_t* Wb = (const uchar_t*)(WihL + (size_t)dir*1024*DMODEL);
  ushort_t* Cb = dir ? outB : outF;
  const float* bb = bsumL + dir*1024;

  int lane = tid & 63, w = tid >> 6;
  int wm = w >> 1, wn = w & 1;          // 64x64 quadrant per wave
  int r = lane & 15, hi = lane >> 4;
  int srow = tid >> 3;                  // 0..31
  int sslot = (tid & 7) * 16;
  float4v acc[4][4] = {};

  for(int kt=0; kt<8; ++kt){
    #pragma unroll
    for(int i=0;i<4;++i){
      int row = i*32 + srow;
      int src = sslot ^ ((row & 7) << 4);
      gload16(Ab + (size_t)row*1024 + (size_t)kt*128 + src,
              As + i*4096 + w*1024);
      gload16(Wb + (size_t)(i*256 + tu*32 + srow)*1024 + (size_t)kt*128 + src,
              Bs + i*4096 + w*1024);
    }
    __syncthreads();
    #pragma unroll
    for(int ks=0; ks<2; ++ks){
      int kb = ks*64 + hi*16;
      short8 af[4], bf[4];
      #pragma unroll
      for(int m=0;m<4;++m){
        int row = wm*64 + m*16 + r;
        af[m] = *(const short8*)(As + row*128 + (kb ^ ((row&7)<<4)));
      }
      #pragma unroll
      for(int n=0;n<4;++n){
        int row = wn*64 + n*16 + r;
        bf[n] = *(const short8*)(Bs + row*128 + (kb ^ ((row&7)<<4)));
      }
      #pragma unroll
      for(int m=0;m<4;++m)
        #pragma unroll
        for(int n=0;n<4;++n)
          acc[m][n] = MFMA(af[m], bf[n], acc[m][n]);
    }
    __syncthreads();
  }
  uchar_t* Cs = smem;
  int cc = lane & 15;
  #pragma unroll
  for(int n=0;n<4;++n){
    int rb = wn*64 + n*16 + cc;
    int g = rb >> 5, ul = rb & 31;
    int cl = (ul << 2) | g;
    float bv = bb[g*256 + tu*32 + ul];
    #pragma unroll
    for(int m=0;m<4;++m){
      #pragma unroll
      for(int j=0;j<4;++j){
        int row = wm*64 + m*16 + hi*4 + j;
        *(ushort_t*)&Cs[row*256 + ((cl*2) ^ ((row&7)<<4))] =
            f2bf(acc[m][n][j] + bv);
      }
    }
  }
  __syncthreads();
  #pragma unroll
  for(int p=0;p<8;++p){
    int idx = p*4096 + tid*16;
    int row = idx >> 8, cb = idx & 255;
    short8 v = *(const short8*)&Cs[row*256 + (cb ^ ((row&7)<<4))];
    *(short8*)&Cb[(size_t)(bm*128 + row)*1024 + tu*128 + (cb>>1)] = v;
  }
}

// ---------------- megakernel: scan(chunk c) + CO-RESIDENT gemm(chunk c+1) -----
// grid = 256 (+1024 when next chunk exists) x 512 thr.
// Blocks 0..255: the proven R8 scan (1 batch-dir/block, 8 waves, 32KB LDS,
//   8/32 wave slots) -- leaves >60% of each CU's wave slots + LDS free.
// Blocks 256+: independent 128x128 GEMM tiles for chunk c+1 (512-thr lane
//   mapping of the proven R8 structure). The HW scheduler backfills 2-3 GEMM
//   blocks per scan CU and interleaves per-cycle (no barrier coupling -- the
//   R5/R6 failure modes). Ordering scan(c+1)<-gemm(c+1) via kernel boundary.
__global__ __launch_bounds__(512,1) void k_scan_gemm(
    const ushort_t* __restrict__ preF,   // scan: [CHUNK*B][1024] dir0 band
    const ushort_t* __restrict__ preB,   // scan: dir1 band
    const uchar_t* __restrict__ Wq,      // [2,1024,256] fp8, k-permuted
    uchar_t* __restrict__ hstate,        // [2,128,256] fp8 (permuted order)
    float* __restrict__ cstate,          // [2,128,256] f32
    ushort_t* __restrict__ xout,         // [S*B,512] bf16
    int t0,
    const ushort_t* __restrict__ xin,    // gemm: layer input
    const ushort_t* __restrict__ WihL,   // gemm: [2,1024,512] bf16
    const float* __restrict__ bsumL,     // gemm: [2,1024]
    ushort_t* __restrict__ outF,         // gemm: band chunk c+1 dir0
    ushort_t* __restrict__ outB,         // gemm: dir1
    int t0n){
  __shared__ __align__(16) uchar_t smem[32768];
  int bid = blockIdx.x;
  int tid = threadIdx.x;

  if(bid < 256){
    // ================= scan path (R8 structure, verbatim) =================
    uchar_t (*hbuf)[288] = (uchar_t(*)[288])smem;     // 2 x 288 B
    int d = bid >> 7, b = bid & 127;
    int w = tid >> 6, lane = tid & 63;
    int lo = lane & 15, hi = lane >> 4;
    int u0 = w*32;

    if(tid < 64)
      *(unsigned int*)&hbuf[0][tid*4] =
        *(const unsigned int*)(hstate + ((size_t)d*BATCH + b)*HIDDEN + tid*4);

    int8v wq[4][2][2];
    const uchar_t* Wd = Wq + (size_t)d*1024*HIDDEN;
    #pragma unroll
    for(int g=0; g<4; ++g)
      #pragma unroll
      for(int uh=0; uh<2; ++uh)
        #pragma unroll
        for(int kt=0; kt<2; ++kt)
          wq[g][uh][kt] = *(const int8v*)
            (Wd + (size_t)(g*256 + u0 + uh*16 + lo)*HIDDEN + kt*128 + hi*32);

    float c[2];
    #pragma unroll
    for(int uh=0; uh<2; ++uh)
      c[uh] = cstate[((size_t)d*BATCH + b)*HIDDEN + u0 + uh*16 + lo];

    const ushort_t* pp = (d ? preB : preF) + (size_t)b*1024;
    ushort4 pc[2], pn[2];
    {
      int br = d ? (CHUNK-1) : 0;
      if(hi==0){
        #pragma unroll
        for(int uh=0; uh<2; ++uh)
          pc[uh] = *(const ushort4*)(pp + (size_t)br*BATCH*1024 + (u0+uh*16+lo)*4);
      }
    }
    __syncthreads();

    for(int sb=0; sb<CHUNK; ++sb){
      int p = sb & 1;
      int sb2 = (sb+1 < CHUNK) ? sb+1 : sb;
      int br2 = d ? (CHUNK-1-sb2) : sb2;
      if(hi==0){
        #pragma unroll
        for(int uh=0; uh<2; ++uh)
          pn[uh] = *(const ushort4*)(pp + (size_t)br2*BATCH*1024 + (u0+uh*16+lo)*4);
      }

      int8v ha0 = {0,0,0,0,0,0,0,0};
      int8v ha1 = {0,0,0,0,0,0,0,0};
      if(lo==0){
        ha0 = *(const int8v*)&hbuf[p][hi*32];          // k 0..127
        ha1 = *(const int8v*)&hbuf[p][128 + hi*32];    // k 128..255
      }
      float4v acc[4][2] = {};
      #pragma unroll
      for(int g=0; g<4; ++g){
        acc[g][0] = MFMAMX(ha0, wq[g][0][0], acc[g][0]);
        acc[g][1] = MFMAMX(ha0, wq[g][1][0], acc[g][1]);
        acc[g][0] = MFMAMX(ha1, wq[g][0][1], acc[g][0]);
        acc[g][1] = MFMAMX(ha1, wq[g][1][1], acc[g][1]);
      }

      int s = t0 + sb;
      int s_eff = d ? (S_LEN-1-s) : s;
      if(hi==0){
        float hnv[2];
        #pragma unroll
        for(int uh=0; uh<2; ++uh){
          float gi = acc[0][uh][0] + bf2f(pc[uh].x);
          float gf = acc[1][uh][0] + bf2f(pc[uh].y);
          float gg = acc[2][uh][0] + bf2f(pc[uh].z);
          float go = acc[3][uh][0] + bf2f(pc[uh].w);
          float cn = sigm(gf)*c[uh] + sigm(gi)*tanh_f(gg);
          float hn = sigm(go)*tanh_f(cn);
          c[uh] = cn;
          hnv[uh] = hn;
          int u = u0 + uh*16 + lo;
          xout[((size_t)s_eff*BATCH + b)*DMODEL + d*HIDDEN + u] = f2bf(hn);
        }
#if __has_builtin(__builtin_amdgcn_cvt_pk_fp8_f32)
        int pk = __builtin_amdgcn_cvt_pk_fp8_f32(hnv[0], hnv[1], 0, false);
        *(ushort_t*)&hbuf[p^1][u0 + 2*lo] = (ushort_t)pk;
#else
        hbuf[p^1][u0 + 2*lo]     = f2fp8(hnv[0]);
        hbuf[p^1][u0 + 2*lo + 1] = f2fp8(hnv[1]);
#endif
      }
      asm volatile("s_waitcnt lgkmcnt(0)\n\ts_barrier" ::: "memory");
      #pragma unroll
      for(int uh=0; uh<2; ++uh) pc[uh] = pn[uh];
    }

    if(tid < 64)
      *(unsigned int*)(hstate + ((size_t)d*BATCH + b)*HIDDEN + tid*4) =
        *(const unsigned int*)&hbuf[0][tid*4];
    if(hi==0){
      #pragma unroll
      for(int uh=0; uh<2; ++uh)
        cstate[((size_t)d*BATCH + b)*HIDDEN + u0 + uh*16 + lo] = c[uh];
    }
  } else {
    // ================= gemm path (chunk c+1), 512-thr lane mapping =========
    int gid = bid - 256;                  // 0..1023
    int tu  = gid & 7;                    // unit-block
    int rest = gid >> 3;                  // 0..127
    int dir = rest >> 6, bm = rest & 63;  // 64 M-tiles per dir at CHUNK=64
    uchar_t* As = smem;
    uchar_t* Bs = smem + 16384;
    const uchar_t* Ab = (const uchar_t*)(xin +
        (size_t)(dir ? (S_LEN - t0n - CHUNK) : t0n)*BATCH*DMODEL +
        (size_t)bm*128*DMODEL);
    const uchar_t* Wb = (const uchar_t*)(WihL + (size_t)dir*1024*DMODEL);
    ushort_t* Cb = dir ? outB : outF;
    const float* bb = bsumL + dir*1024;

    int lane = tid & 63, w = tid >> 6;    // 8 waves
    int wm = w >> 2, wn = w & 3;          // 2x4 quadrants: wave tile 64x32
    int r = lane & 15, hi = lane >> 4;
    int srow = tid >> 3;                  // 0..63
    int sslot = (tid & 7) * 16;
    float4v acc[4][2] = {};

    for(int kt=0; kt<8; ++kt){
      #pragma unroll
      for(int i=0;i<2;++i){
        int row = i*64 + srow;            // 0..127
        int src = sslot ^ ((row & 7) << 4);
        gload16(Ab + (size_t)row*1024 + (size_t)kt*128 + src,
                As + i*8192 + w*1024);
        gload16(Wb + (size_t)((row>>5)*256 + tu*32 + (row&31))*1024
                   + (size_t)kt*128 + src,
                Bs + i*8192 + w*1024);
      }
      __syncthreads();
      #pragma unroll
      for(int ks=0; ks<2; ++ks){
        int kb = ks*64 + hi*16;
        short8 af[4], bf[2];
        #pragma unroll
        for(int m=0;m<4;++m){
          int row = wm*64 + m*16 + r;
          af[m] = *(const short8*)(As + row*128 + (kb ^ ((row&7)<<4)));
        }
        #pragma unroll
        for(int n=0;n<2;++n){
          int row = wn*32 + n*16 + r;
          bf[n] = *(const short8*)(Bs + row*128 + (kb ^ ((row&7)<<4)));
        }
        #pragma unroll
        for(int m=0;m<4;++m)
          #pragma unroll
          for(int n=0;n<2;++n)
            acc[m][n] = MFMA(af[m], bf[n], acc[m][n]);
      }
      __syncthreads();
    }
    uchar_t* Cs = smem;
    int cc = lane & 15;
    #pragma unroll
    for(int n=0;n<2;++n){
      int rb = wn*32 + n*16 + cc;                    // staged B row = out idx
      int g = rb >> 5, ul = rb & 31;
      int cl = (ul << 2) | g;
      float bv = bb[g*256 + tu*32 + ul];
      #pragma unroll
      for(int m=0;m<4;++m){
        #pragma unroll
        for(int j=0;j<4;++j){
          int row = wm*64 + m*16 + hi*4 + j;
          *(ushort_t*)&Cs[row*256 + ((cl*2) ^ ((row&7)<<4))] =
              f2bf(acc[m][n][j] + bv);
        }
      }
    }
    __syncthreads();
    #pragma unroll
    for(int p=0;p<4;++p){
      int idx = p*8192 + tid*16;
      int row = idx >> 8, cb = idx & 255;
      short8 v = *(const short8*)&Cs[row*256 + (cb ^ ((row&7)<<4))];
      *(short8*)&Cb[(size_t)(bm*128 + row)*1024 + tu*128 + (cb>>1)] = v;
    }
  }
}

// ---------------- logits via MFMA: [M,32] = x[M,512] @ W_lin^T + b_lin --------
__global__ __launch_bounds__(256) void k_logits(const ushort_t* __restrict__ x,
                                                const ushort_t* __restrict__ Wl,
                                                const float* __restrict__ bl,
                                                float* __restrict__ logits){
  int tid = threadIdx.x;
  int lane = tid & 63, w = tid >> 6;
  int rowb = blockIdx.x*64 + w*16;      // wave's 16-row strip
  int r = lane & 15, hi = lane >> 4;
  float4v acc[2] = {};
  #pragma unroll
  for(int kt=0; kt<16; ++kt){
    short8 a  = *(const short8*)&x [(size_t)(rowb + r)*DMODEL + kt*32 + hi*8];
    short8 b0 = *(const short8*)&Wl[(size_t)(r     )*DMODEL + kt*32 + hi*8];
    short8 b1 = *(const short8*)&Wl[(size_t)(16 + r)*DMODEL + kt*32 + hi*8];
    acc[0] = MFMA(a, b0, acc[0]);
    acc[1] = MFMA(a, b1, acc[1]);
  }
  #pragma unroll
  for(int nt=0; nt<2; ++nt){
    float bv = bl[nt*16 + r];
    #pragma unroll
    for(int j=0; j<4; ++j)
      logits[(size_t)(rowb + hi*4 + j)*NTAGS + nt*16 + r] = acc[nt][j] + bv;
  }
}

// ---------------- CRF partition: per-batch alpha recurrence ------------------
__global__ __launch_bounds__(64) void k_crf(const float* __restrict__ logits,
                                            const float* __restrict__ trans,
                                            float* __restrict__ logz){
  __shared__ __align__(16) float sh[32];
  int b = blockIdx.x, tid = threadIdx.x;
  int t = tid & 31;                       // lanes 32-63 mirror 0-31

  float eT[32];
  #pragma unroll
  for(int j=0;j<32;++j) eT[j] = __expf(trans[j*NTAGS + t]);

  float al0 = logits[(size_t)b*NTAGS + t];
  float m0 = al0;
  #pragma unroll
  for(int o=1;o<32;o<<=1) m0 = fmaxf(m0, __shfl_xor(m0, o));
  float Mf = m0;
  float a = __expf(al0 - m0);

  const size_t stp = (size_t)BATCH*NTAGS;
  const float* ebase = logits + (size_t)b*NTAGS + t;
  float eCur = ebase[stp*1];
  float eNxt = ebase[stp*2];
  const float* eptr = ebase + stp*3;

  for(int i=1;i<S_LEN;++i){
    float expE = __expf(eCur);
    if(tid < 32) sh[t] = a;
    __syncthreads();
    float eP = 0.f;
    if(i+2 < S_LEN) eP = *eptr;
    eptr += stp;
    float s0=0.f, s1=0.f, s2=0.f, s3=0.f;
    const float4v* s4 = (const float4v*)sh;
    #pragma unroll
    for(int q=0;q<8;++q){
      float4v v = s4[q];
      s0 = __fmaf_rn(v[0], eT[q*4+0], s0);
      s1 = __fmaf_rn(v[1], eT[q*4+1], s1);
      s2 = __fmaf_rn(v[2], eT[q*4+2], s2);
      s3 = __fmaf_rn(v[3], eT[q*4+3], s3);
    }
    a = ((s0+s1)+(s2+s3)) * expE;
    eCur = eNxt; eNxt = eP;
    if(__any(a > 1.1529215e18f) || __all(a < 9.0949470e-13f)){   // 2^60 / 2^-40
      float m = a;
      #pragma unroll
      for(int o=1;o<32;o<<=1) m = fmaxf(m, __shfl_xor(m, o));
      int e2 = (int)((__float_as_uint(m)>>23)&255u) - 127;
      float scl = __uint_as_float((unsigned)(127 - e2) << 23);
      a *= scl;
      Mf += (float)e2 * 0.69314718055994531f;
    }
    __syncthreads();
  }
  float sum = a;
  #pragma unroll
  for(int o=1;o<32;o<<=1) sum += __shfl_xor(sum, o);
  if(tid==0) logz[b] = Mf + __logf(sum);
}

// ---------------- gold path score + combine ----------------------------------
__global__ __launch_bounds__(256) void k_gold(const float* __restrict__ logits,
                                              const int* __restrict__ tgt,
                                              const float* __restrict__ trans,
                                              const float* __restrict__ logz,
                                              float* __restrict__ partial){
  int b = blockIdx.x, tid = threadIdx.x;
  float local = 0.f;
  for(int s=tid; s<S_LEN; s+=256){
    int ts = tgt[s*BATCH + b];
    local += logits[((size_t)s*BATCH + b)*NTAGS + ts];
    if(s > 0){
      int tp = tgt[(s-1)*BATCH + b];
      local += trans[tp*NTAGS + ts];
    }
  }
  __shared__ float red[4];
  for(int o=32;o>0;o>>=1) local += __shfl_down(local, o, 64);
  if((tid&63)==0) red[tid>>6] = local;
  __syncthreads();
  if(tid==0) partial[b] = logz[b] - (red[0]+red[1]+red[2]+red[3]);
}
__global__ __launch_bounds__(128) void k_final(const float* __restrict__ partial,
                                               float* __restrict__ out){
  int t = threadIdx.x;
  float v = partial[t];
  for(int o=32;o>0;o>>=1) v += __shfl_down(v, o, 64);
  __shared__ float r2[2];
  if((t&63)==0) r2[t>>6] = v;
  __syncthreads();
  if(t==0) out[0] = (r2[0]+r2[1]) * (1.0f/BATCH);
}

// ---------------- launcher ---------------------------------------------------
extern "C" void kernel_launch(void* const* d_in, const int* in_sizes, int n_in,
                              void* d_out, int out_size, void* d_ws, size_t ws_size,
                              hipStream_t stream){
  const int*   src   = (const int*)d_in[0];
  const int*   tgt   = (const int*)d_in[1];
  const float* emb   = (const float*)d_in[2];
  const float* Wih   = (const float*)d_in[3];
  const float* Whh   = (const float*)d_in[4];
  const float* bih   = (const float*)d_in[5];
  const float* bhh   = (const float*)d_in[6];
  const float* Wlin  = (const float*)d_in[7];
  const float* blin  = (const float*)d_in[8];
  const float* trans = (const float*)d_in[9];
  float* out = (float*)d_out;
  char* ws = (char*)d_ws;

  // workspace layout — total ~197.4 MB (unchanged footprint)
  const size_t BSZ = (size_t)CHUNK*BATCH*1024*sizeof(ushort_t);   // 16.78 MB/band
  ushort_t* xA     = (ushort_t*)(ws + 0);              //  67,108,864
  ushort_t* xB     = (ushort_t*)(ws + 67108864);       //  67,108,864
  char*     bands  =             ws + 134217728;       //  4 x 16.78 MB (F0,B0,F1,B1)
  ushort_t* bF[2]  = { (ushort_t*)(bands),           (ushort_t*)(bands + 2*BSZ) };
  ushort_t* bB[2]  = { (ushort_t*)(bands + BSZ),     (ushort_t*)(bands + 3*BSZ) };
  ushort_t* WihB   = (ushort_t*)(ws + 201326592);      //   4,194,304
  uchar_t*  Wq8    = (uchar_t*) (ws + 205520896);      //   1,048,576 fp8 Whh (k-perm)
  ushort_t* WlinB  = (ushort_t*)(ws + 206569472);      //      32,768
  float*    bsum   = (float*)   (ws + 206602240);      //      16,384
  uchar_t*  hstate = (uchar_t*) (ws + 206618624);      //      65,536 fp8
  float*    cstate = (float*)   (ws + 206684160);      //     262,144
  float*    logz   = (float*)   (ws + 206946304);      //         512
  float*    partial= (float*)   (ws + 206946816);      //         512
  float*    logits = (float*)   (ws + 134217728);      // aliases bands (dead by then)

  // weight conversions
  k_cvt_bf16<<<dim3(8192),dim3(256),0,stream>>>(Wih,  WihB,  2*2*1024*512);
  k_cvt_fp8p<<<dim3(4096),dim3(256),0,stream>>>(Whh,  Wq8,   2*2*1024*256);
  k_cvt_bf16<<<dim3(64),  dim3(256),0,stream>>>(Wlin, WlinB, 32*512);
  k_biassum <<<dim3(16),  dim3(256),0,stream>>>(bih, bhh, bsum, 2*2*1024);

  // embedding
  k_embed<<<dim3(MROWS),dim3(64),0,stream>>>(src, emb, xA);

  for(int l=0;l<2;++l){
    const ushort_t* xin = l ? xB : xA;
    ushort_t*      xo   = l ? xA : xB;
    hipMemsetAsync(hstate, 0, 65536 + 262144, stream);
    const uchar_t*  WqL   = Wq8  + (size_t)l*2*1024*HIDDEN;
    const ushort_t* WihL  = WihB + (size_t)l*2*1024*DMODEL;
    const float*    bsumL = bsum + l*2*1024;
    // prologue: chunk 0 bands, both dirs (full chip, 256-thr tiles)
    k_gemm_band<<<dim3(8, CHUNK*BATCH/128, 2),dim3(256),0,stream>>>(
        xin, 0, WihL, bsumL, bF[0], bB[0]);
    for(int c=0;c<NCH;++c){
      int par = c & 1;
      int t0 = c*CHUNK;
      int ngem = (c+1 < NCH) ? 1 : 0;
      // scan(c) + co-resident gemm(c+1): extra 1024 blocks only when needed
      k_scan_gemm<<<dim3(ngem ? 1280 : 256),dim3(512),0,stream>>>(
          bF[par], bB[par], WqL, hstate, cstate, xo, t0,
          xin, WihL, bsumL, bF[par^1], bB[par^1], t0 + CHUNK);
    }
  }

  k_logits<<<dim3(MROWS/64),dim3(256),0,stream>>>(xA, WlinB, blin, logits);
  k_crf   <<<dim3(BATCH),dim3(64),0,stream>>>(logits, trans, logz);
  k_gold  <<<dim3(BATCH),dim3(256),0,stream>>>(logits, tgt, trans, logz, partial);
  k_final <<<dim3(1),dim3(128),0,stream>>>(partial, out);
}

// Round 11
// 2113.338 us; speedup vs baseline: 1.0864x; 1.0864x over previous
//
#include <hip/hip_runtime.h>
#include <math.h>

typedef __attribute__((ext_vector_type(8))) short short8;
typedef __attribute__((ext_vector_type(4))) float float4v;
typedef __attribute__((ext_vector_type(8))) int int8v;
typedef unsigned short ushort_t;
typedef unsigned char uchar_t;

#define S_LEN 512
#define BATCH 128
#define DMODEL 512
#define HIDDEN 256
#define NTAGS 32
#define MROWS (S_LEN*BATCH)
#define CHUNK 128                 // sequence steps per pre-band
#define NCH (S_LEN/CHUNK)         // 4 chunks
#define EMB_SCALE 22.62741699796952f

__device__ __forceinline__ float bf2f(ushort_t u){
  union { unsigned int i; float f; } v; v.i = ((unsigned int)u)<<16; return v.f;
}
__device__ __forceinline__ ushort_t f2bf(float f){
  union { float f; unsigned int i; } v; v.f = f;
  unsigned int x = v.i;
  x += 0x7fffu + ((x>>16)&1u);
  return (ushort_t)(x>>16);
}
// float -> OCP e4m3fn, RNE, saturate to 448
__device__ __forceinline__ uchar_t f2fp8(float f){
  float a = fabsf(f);
  unsigned int s = (__float_as_uint(f) >> 24) & 0x80u;
  if (a >= 448.f) return (uchar_t)(s | 0x7Eu);
  if (a < 0.015625f){                         // subnormal: m = round(a*512)
    unsigned int q = (unsigned int)__float2int_rn(a * 512.0f);
    return (uchar_t)(s | q);
  }
  unsigned int x = __float_as_uint(a);
  x += 0x7FFFFu + ((x >> 20) & 1u);           // RNE into 3-bit mantissa
  int e = (int)((x >> 23) & 0xFFu) - 127;
  unsigned int m = (x >> 20) & 7u;
  if (e > 8) return (uchar_t)(s | 0x7Eu);
  return (uchar_t)(s | ((unsigned)(e + 7) << 3) | m);
}
__device__ __forceinline__ float sigm(float x){ return 1.0f/(1.0f+__expf(-x)); }
__device__ __forceinline__ float tanh_f(float x){ return 2.0f/(1.0f+__expf(-2.0f*x)) - 1.0f; }

#define MFMA(a,b,c) __builtin_amdgcn_mfma_f32_16x16x32_bf16(a,b,c,0,0,0)
// block-scaled MX fp8 MFMA, K=128, unit scales (e8m0 0x7F = 2^0)
#define MFMAMX(a,b,c) __builtin_amdgcn_mfma_scale_f32_16x16x128_f8f6f4( \
    a, b, c, 0, 0, 0, 0x7F7F7F7F, 0, 0x7F7F7F7F)

// direct global->LDS 16B copy: wave-uniform LDS base + lane*16; global per-lane
typedef const __attribute__((address_space(1))) void gas_void;
typedef __attribute__((address_space(3))) void las_void;
__device__ __forceinline__ void gload16(const void* g, void* l){
  __builtin_amdgcn_global_load_lds((gas_void*)g, (las_void*)l, 16, 0, 0);
}

// ---------------- elementwise helpers ----------------
__global__ void k_cvt_bf16(const float* __restrict__ s, ushort_t* __restrict__ d, int n){
  int i = blockIdx.x*blockDim.x + threadIdx.x;
  if(i<n) d[i] = f2bf(s[i]);
}
// Whh fp8 quant with k-permutation: pos q holds unit u = 32*(q>>5)+16*(q&1)+((q>>1)&15)
// (so the scan can store h pairs (u0+lo, u0+16+lo) as one packed ushort at u0+2*lo)
__global__ void k_cvt_fp8p(const float* __restrict__ s, uchar_t* __restrict__ d, int n){
  int i = blockIdx.x*blockDim.x + threadIdx.x;
  if(i<n){
    int row = i >> 8, q = i & 255;
    int u = ((q >> 5) << 5) + ((q & 1) << 4) + ((q >> 1) & 15);
    d[i] = f2fp8(s[row*256 + u]);
  }
}
__global__ void k_biassum(const float* __restrict__ a, const float* __restrict__ b,
                          float* __restrict__ o, int n){
  int i = blockIdx.x*blockDim.x + threadIdx.x;
  if(i<n) o[i] = a[i]+b[i];
}

// ---------------- embedding: x[s,b,:] = emb[src[s,b],:]*sqrt(D)  (bf16 out) ----
__global__ __launch_bounds__(64) void k_embed(const int* __restrict__ src,
                                              const float* __restrict__ emb,
                                              ushort_t* __restrict__ x){
  int row = blockIdx.x;            // 0..65535  (= s*BATCH+b)
  int t = threadIdx.x;             // 64 threads, 8 elems each
  int tok = src[row];
  const float4v* e = (const float4v*)(emb + (size_t)tok*DMODEL + t*8);
  float4v a = e[0], b = e[1];
  short8 o;
  o[0]=(short)f2bf(a[0]*EMB_SCALE); o[1]=(short)f2bf(a[1]*EMB_SCALE);
  o[2]=(short)f2bf(a[2]*EMB_SCALE); o[3]=(short)f2bf(a[3]*EMB_SCALE);
  o[4]=(short)f2bf(b[0]*EMB_SCALE); o[5]=(short)f2bf(b[1]*EMB_SCALE);
  o[6]=(short)f2bf(b[2]*EMB_SCALE); o[7]=(short)f2bf(b[3]*EMB_SCALE);
  *(short8*)(x + (size_t)row*DMODEL + t*8) = o;
}

// ---------------- band pre-GEMM, 128x128 tile, gate-blocked N ------------------
// C[Mband,1024] = A[Mband,512] @ W[1024,512]^T + bias. N-tile = 4 gates x 32
// units (tu = blockIdx.x): its 128 interleaved output cols (colp = u*4+g) are
// CONTIGUOUS [tu*128,+128) -> epilogue repacks acc via LDS and stores fully
// coalesced short8. Staging: global_load_lds w16, source XOR-swizzled.
__global__ __launch_bounds__(256) void k_gemm_band(
    const ushort_t* __restrict__ xin, int t0,
    const ushort_t* __restrict__ WihL,   // [2,1024,512] bf16
    const float* __restrict__ bsumL,     // [2,1024]
    ushort_t* __restrict__ outF,         // [CHUNK*B,1024] dir0
    ushort_t* __restrict__ outB){        // dir1
  __shared__ __align__(16) uchar_t smem[32768];   // As 16K | Bs 16K ; Cs 32K (reuse)
  uchar_t* As = smem;
  uchar_t* Bs = smem + 16384;
  int tid = threadIdx.x;
  int tu = blockIdx.x;                  // 0..7  unit-block (32 units x 4 gates)
  int by = blockIdx.y;                  // 0..255
  int dir = by >> 7, bm = by & 127;     // 128-row tile of Mband=16384
  const uchar_t* Ab = (const uchar_t*)(xin +
      (size_t)(dir ? (S_LEN - t0 - CHUNK) : t0)*BATCH*DMODEL +
      (size_t)bm*128*DMODEL);
  const uchar_t* Wb = (const uchar_t*)(WihL + (size_t)dir*1024*DMODEL);
  ushort_t* Cb = dir ? outB : outF;
  const float* bb = bsumL + dir*1024;

  int lane = tid & 63, w = tid >> 6;
  int wm = w >> 1, wn = w & 1;          // 64x64 quadrant per wave
  int r = lane & 15, hi = lane >> 4;
  int srow = tid >> 3;                  // 0..31
  int sslot = (tid & 7) * 16;
  float4v acc[4][4] = {};

  for(int kt=0; kt<8; ++kt){            // K-tiles of 64 (128 B of each row)
    #pragma unroll
    for(int i=0;i<4;++i){
      int row = i*32 + srow;
      int src = sslot ^ ((row & 7) << 4);     // inverse swizzle on source
      gload16(Ab + (size_t)row*1024 + (size_t)kt*128 + src,
              As + i*4096 + w*1024);
      // B rows: gate i, units [tu*32, +32)
      gload16(Wb + (size_t)(i*256 + tu*32 + srow)*1024 + (size_t)kt*128 + src,
              Bs + i*4096 + w*1024);
    }
    __syncthreads();
    #pragma unroll
    for(int ks=0; ks<2; ++ks){          // 2 MFMA k-steps (K=32 each)
      int kb = ks*64 + hi*16;
      short8 af[4], bf[4];
      #pragma unroll
      for(int m=0;m<4;++m){
        int row = wm*64 + m*16 + r;
        af[m] = *(const short8*)(As + row*128 + (kb ^ ((row&7)<<4)));
      }
      #pragma unroll
      for(int n=0;n<4;++n){
        int row = wn*64 + n*16 + r;
        bf[n] = *(const short8*)(Bs + row*128 + (kb ^ ((row&7)<<4)));
      }
      #pragma unroll
      for(int m=0;m<4;++m)
        #pragma unroll
        for(int n=0;n<4;++n)
          acc[m][n] = MFMA(af[m], bf[n], acc[m][n]);
    }
    __syncthreads();
  }
  // epilogue: acc -> LDS (local interleave, XOR-swizzled rows) -> coalesced store
  uchar_t* Cs = smem;
  int cc = lane & 15;
  #pragma unroll
  for(int n=0;n<4;++n){
    int rb = wn*64 + n*16 + cc;                    // staged B row = output idx
    int g = rb >> 5, ul = rb & 31;
    int cl = (ul << 2) | g;                        // local interleaved col
    float bv = bb[g*256 + tu*32 + ul];
    #pragma unroll
    for(int m=0;m<4;++m){
      #pragma unroll
      for(int j=0;j<4;++j){
        int row = wm*64 + m*16 + hi*4 + j;
        *(ushort_t*)&Cs[row*256 + ((cl*2) ^ ((row&7)<<4))] =
            f2bf(acc[m][n][j] + bv);
      }
    }
  }
  __syncthreads();
  #pragma unroll
  for(int p=0;p<8;++p){
    int idx = p*4096 + tid*16;
    int row = idx >> 8, cb = idx & 255;
    short8 v = *(const short8*)&Cs[row*256 + (cb ^ ((row&7)<<4))];
    *(short8*)&Cb[(size_t)(bm*128 + row)*1024 + tu*128 + (cb>>1)] = v;
  }
}

// ---------------- per-batch bidirectional LSTM scan over one CHUNK ------------
// grid = 256 blocks x 512 threads: bid = d*128 + b. ONE batch element per
// block. MX-scaled fp8 MFMA (16x16x128): 16 MFMA/wave/step.
// h stored in PERMUTED order (pos u0+2*lo+uh = unit u0+16*uh+lo) matching
// Wq's permuted k-dim -> one v_cvt_pk_fp8_f32 + one 2B store per cell lane.
__global__ __launch_bounds__(512,1) void k_scan3(
    const ushort_t* __restrict__ preF,   // [CHUNK*B][1024] gate-interleaved dir0
    const ushort_t* __restrict__ preB,   // same, dir1 band
    const uchar_t* __restrict__ Wq,      // [2,1024,256] fp8, k-permuted
    uchar_t* __restrict__ hstate,        // [2,128,256] fp8 (permuted order)
    float* __restrict__ cstate,          // [2,128,256] f32
    ushort_t* __restrict__ xout,         // [S*B,512] bf16
    int t0){
  __shared__ __align__(16) uchar_t hbuf[2][288];   // h vector only (256B + pad)
  int bid = blockIdx.x;
  int d = bid >> 7, b = bid & 127;
  int tid = threadIdx.x;
  int w = tid >> 6, lane = tid & 63;
  int lo = lane & 15, hi = lane >> 4;
  int u0 = w*32;                           // wave's unit base [0,256)

  if(tid < 64)
    *(unsigned int*)&hbuf[0][tid*4] =
      *(const unsigned int*)(hstate + ((size_t)d*BATCH + b)*HIDDEN + tid*4);

  // fp8 weights -> 128 VGPRs/lane: wq[g][uh][kt] (k-dim already permuted)
  int8v wq[4][2][2];
  const uchar_t* Wd = Wq + (size_t)d*1024*HIDDEN;
  #pragma unroll
  for(int g=0; g<4; ++g)
    #pragma unroll
    for(int uh=0; uh<2; ++uh)
      #pragma unroll
      for(int kt=0; kt<2; ++kt)
        wq[g][uh][kt] = *(const int8v*)
          (Wd + (size_t)(g*256 + u0 + uh*16 + lo)*HIDDEN + kt*128 + hi*32);

  float c[2];
  #pragma unroll
  for(int uh=0; uh<2; ++uh)
    c[uh] = cstate[((size_t)d*BATCH + b)*HIDDEN + u0 + uh*16 + lo];

  const ushort_t* pp = (d ? preB : preF) + (size_t)b*1024;
  ushort4 pc[2], pn[2];
  {
    int br = d ? (CHUNK-1) : 0;
    if(hi==0){
      #pragma unroll
      for(int uh=0; uh<2; ++uh)
        pc[uh] = *(const ushort4*)(pp + (size_t)br*BATCH*1024 + (u0+uh*16+lo)*4);
    }
  }
  __syncthreads();

  for(int sb=0; sb<CHUNK; ++sb){
    int p = sb & 1;
    int sb2 = (sb+1 < CHUNK) ? sb+1 : sb;
    int br2 = d ? (CHUNK-1-sb2) : sb2;
    if(hi==0){
      #pragma unroll
      for(int uh=0; uh<2; ++uh)
        pn[uh] = *(const ushort4*)(pp + (size_t)br2*BATCH*1024 + (u0+uh*16+lo)*4);
    }

    int8v ha0 = {0,0,0,0,0,0,0,0};
    int8v ha1 = {0,0,0,0,0,0,0,0};
    if(lo==0){
      ha0 = *(const int8v*)&hbuf[p][hi*32];          // k 0..127
      ha1 = *(const int8v*)&hbuf[p][128 + hi*32];    // k 128..255
    }
    float4v acc[4][2] = {};
    #pragma unroll
    for(int g=0; g<4; ++g){
      acc[g][0] = MFMAMX(ha0, wq[g][0][0], acc[g][0]);
      acc[g][1] = MFMAMX(ha0, wq[g][1][0], acc[g][1]);
      acc[g][0] = MFMAMX(ha1, wq[g][0][1], acc[g][0]);
      acc[g][1] = MFMAMX(ha1, wq[g][1][1], acc[g][1]);
    }

    int s = t0 + sb;
    int s_eff = d ? (S_LEN-1-s) : s;
    if(hi==0){
      float hnv[2];
      #pragma unroll
      for(int uh=0; uh<2; ++uh){
        float gi = acc[0][uh][0] + bf2f(pc[uh].x);
        float gf = acc[1][uh][0] + bf2f(pc[uh].y);
        float gg = acc[2][uh][0] + bf2f(pc[uh].z);
        float go = acc[3][uh][0] + bf2f(pc[uh].w);
        float cn = sigm(gf)*c[uh] + sigm(gi)*tanh_f(gg);
        float hn = sigm(go)*tanh_f(cn);
        c[uh] = cn;
        hnv[uh] = hn;
        int u = u0 + uh*16 + lo;
        xout[((size_t)s_eff*BATCH + b)*DMODEL + d*HIDDEN + u] = f2bf(hn);
      }
#if __has_builtin(__builtin_amdgcn_cvt_pk_fp8_f32)
      int pk = __builtin_amdgcn_cvt_pk_fp8_f32(hnv[0], hnv[1], 0, false);
      *(ushort_t*)&hbuf[p^1][u0 + 2*lo] = (ushort_t)pk;
#else
      hbuf[p^1][u0 + 2*lo]     = f2fp8(hnv[0]);
      hbuf[p^1][u0 + 2*lo + 1] = f2fp8(hnv[1]);
#endif
    }
    asm volatile("s_waitcnt lgkmcnt(0)\n\ts_barrier" ::: "memory");
    #pragma unroll
    for(int uh=0; uh<2; ++uh) pc[uh] = pn[uh];
  }

  if(tid < 64)
    *(unsigned int*)(hstate + ((size_t)d*BATCH + b)*HIDDEN + tid*4) =
      *(const unsigned int*)&hbuf[0][tid*4];
  if(hi==0){
    #pragma unroll
    for(int uh=0; uh<2; ++uh)
      cstate[((size_t)d*BATCH + b)*HIDDEN + u0 + uh*16 + lo] = c[uh];
  }
}

// ---------------- logits via MFMA: [M,32] = x[M,512] @ W_lin^T + b_lin --------
__global__ __launch_bounds__(256) void k_logits(const ushort_t* __restrict__ x,
                                                const ushort_t* __restrict__ Wl,
                                                const float* __restrict__ bl,
                                                float* __restrict__ logits){
  int tid = threadIdx.x;
  int lane = tid & 63, w = tid >> 6;
  int rowb = blockIdx.x*64 + w*16;      // wave's 16-row strip
  int r = lane & 15, hi = lane >> 4;
  float4v acc[2] = {};
  #pragma unroll
  for(int kt=0; kt<16; ++kt){
    short8 a  = *(const short8*)&x [(size_t)(rowb + r)*DMODEL + kt*32 + hi*8];
    short8 b0 = *(const short8*)&Wl[(size_t)(r     )*DMODEL + kt*32 + hi*8];
    short8 b1 = *(const short8*)&Wl[(size_t)(16 + r)*DMODEL + kt*32 + hi*8];
    acc[0] = MFMA(a, b0, acc[0]);
    acc[1] = MFMA(a, b1, acc[1]);
  }
  #pragma unroll
  for(int nt=0; nt<2; ++nt){
    float bv = bl[nt*16 + r];
    #pragma unroll
    for(int j=0; j<4; ++j)
      logits[(size_t)(rowb + hi*4 + j)*NTAGS + nt*16 + r] = acc[nt][j] + bv;
  }
}

// ---------------- CRF partition: per-batch alpha recurrence ------------------
// Single wave64 per batch; NO barriers (per-wave DS ops are in-order, so the
// write->read RAW and read->next-write WAR are program-order-guaranteed).
// Matvec split across lane halves: lane t sums j in [0,16), lane t+32 sums
// j in [16,32) (4 ds_read_b128 + 16 FMA each); one shfl_xor(32) combines.
// Exact power-of-2 renorm on wave-uniform trigger (unchanged numerics).
__global__ __launch_bounds__(64) void k_crf(const float* __restrict__ logits,
                                            const float* __restrict__ trans,
                                            float* __restrict__ logz){
  __shared__ __align__(16) float sh[32];
  int b = blockIdx.x, tid = threadIdx.x;
  int t = tid & 31;                       // tag column
  int half = tid >> 5;                    // 0: j=0..15, 1: j=16..31

  // per-lane half-column of exp(T): eT[j] = exp(trans[half*16+j][t])
  float eT[16];
  #pragma unroll
  for(int j=0;j<16;++j) eT[j] = __expf(trans[(half*16 + j)*NTAGS + t]);

  // init: alpha0 = logits[0,b,:]; a = exp(alpha0 - m0), M = m0
  float al0 = logits[(size_t)b*NTAGS + t];
  float m0 = al0;
  #pragma unroll
  for(int o=1;o<32;o<<=1) m0 = fmaxf(m0, __shfl_xor(m0, o));
  float Mf = m0;
  float a = __expf(al0 - m0);

  const size_t stp = (size_t)BATCH*NTAGS;
  const float* ebase = logits + (size_t)b*NTAGS + t;
  float eCur = ebase[stp*1];              // emission for step 1
  float eNxt = ebase[stp*2];              // emission for step 2
  const float* eptr = ebase + stp*3;      // prefetch pointer (step i+2 at i=1)

  for(int i=1;i<S_LEN;++i){
    float expE = __expf(eCur);            // input prefetched 2 steps ago
    if(tid < 32) sh[t] = a;               // in-order DS: no barrier needed
    // prefetch emission for step i+2 (independent of recurrence)
    float eP = 0.f;
    if(i+2 < S_LEN) eP = *eptr;
    eptr += stp;
    // half-matvec: 4 vector reads + 16 FMA per lane, 4 independent chains
    float s0=0.f, s1=0.f, s2=0.f, s3=0.f;
    const float4v* s4 = (const float4v*)sh + half*4;
    #pragma unroll
    for(int q=0;q<4;++q){
      float4v v = s4[q];
      s0 = __fmaf_rn(v[0], eT[q*4+0], s0);
      s1 = __fmaf_rn(v[1], eT[q*4+1], s1);
      s2 = __fmaf_rn(v[2], eT[q*4+2], s2);
      s3 = __fmaf_rn(v[3], eT[q*4+3], s3);
    }
    float ssum = (s0+s1)+(s2+s3);
    ssum += __shfl_xor(ssum, 32);         // combine halves (both get full sum)
    a = ssum * expE;
    eCur = eNxt; eNxt = eP;
    // exact power-of-2 renorm when out of range (wave-uniform branch)
    if(__any(a > 1.1529215e18f) || __all(a < 9.0949470e-13f)){   // 2^60 / 2^-40
      float m = a;
      #pragma unroll
      for(int o=1;o<32;o<<=1) m = fmaxf(m, __shfl_xor(m, o));
      int e2 = (int)((__float_as_uint(m)>>23)&255u) - 127;
      float scl = __uint_as_float((unsigned)(127 - e2) << 23);   // 2^-e2 exact
      a *= scl;
      Mf += (float)e2 * 0.69314718055994531f;
    }
  }
  // logz = M + log(sum_t a)
  float sum = a;
  #pragma unroll
  for(int o=1;o<32;o<<=1) sum += __shfl_xor(sum, o);
  if(tid==0) logz[b] = Mf + __logf(sum);
}

// ---------------- gold path score + combine ----------------------------------
__global__ __launch_bounds__(256) void k_gold(const float* __restrict__ logits,
                                              const int* __restrict__ tgt,
                                              const float* __restrict__ trans,
                                              const float* __restrict__ logz,
                                              float* __restrict__ partial){
  int b = blockIdx.x, tid = threadIdx.x;
  float local = 0.f;
  for(int s=tid; s<S_LEN; s+=256){
    int ts = tgt[s*BATCH + b];
    local += logits[((size_t)s*BATCH + b)*NTAGS + ts];
    if(s > 0){
      int tp = tgt[(s-1)*BATCH + b];
      local += trans[tp*NTAGS + ts];
    }
  }
  __shared__ float red[4];
  for(int o=32;o>0;o>>=1) local += __shfl_down(local, o, 64);
  if((tid&63)==0) red[tid>>6] = local;
  __syncthreads();
  if(tid==0) partial[b] = logz[b] - (red[0]+red[1]+red[2]+red[3]);
}
__global__ __launch_bounds__(128) void k_final(const float* __restrict__ partial,
                                               float* __restrict__ out){
  int t = threadIdx.x;
  float v = partial[t];
  for(int o=32;o>0;o>>=1) v += __shfl_down(v, o, 64);
  __shared__ float r2[2];
  if((t&63)==0) r2[t>>6] = v;
  __syncthreads();
  if(t==0) out[0] = (r2[0]+r2[1]) * (1.0f/BATCH);
}

// ---------------- launcher ---------------------------------------------------
extern "C" void kernel_launch(void* const* d_in, const int* in_sizes, int n_in,
                              void* d_out, int out_size, void* d_ws, size_t ws_size,
                              hipStream_t stream){
  const int*   src   = (const int*)d_in[0];
  const int*   tgt   = (const int*)d_in[1];
  const float* emb   = (const float*)d_in[2];
  const float* Wih   = (const float*)d_in[3];
  const float* Whh   = (const float*)d_in[4];
  const float* bih   = (const float*)d_in[5];
  const float* bhh   = (const float*)d_in[6];
  const float* Wlin  = (const float*)d_in[7];
  const float* blin  = (const float*)d_in[8];
  const float* trans = (const float*)d_in[9];
  float* out = (float*)d_out;
  char* ws = (char*)d_ws;

  // workspace layout — total ~197.4 MB
  ushort_t* xA     = (ushort_t*)(ws + 0);              //  67,108,864
  ushort_t* xB     = (ushort_t*)(ws + 67108864);       //  67,108,864
  ushort_t* preF   = (ushort_t*)(ws + 134217728);      //  33,554,432 [CHUNK*B,1024]
  ushort_t* preB   = (ushort_t*)(ws + 167772160);      //  33,554,432
  ushort_t* WihB   = (ushort_t*)(ws + 201326592);      //   4,194,304
  uchar_t*  Wq8    = (uchar_t*) (ws + 205520896);      //   1,048,576 fp8 Whh (k-perm)
  ushort_t* WlinB  = (ushort_t*)(ws + 206569472);      //      32,768
  float*    bsum   = (float*)   (ws + 206602240);      //      16,384
  uchar_t*  hstate = (uchar_t*) (ws + 206618624);      //      65,536 fp8
  float*    cstate = (float*)   (ws + 206684160);      //     262,144
  float*    logz   = (float*)   (ws + 206946304);      //         512
  float*    partial= (float*)   (ws + 206946816);      //         512
  float*    logits = (float*)   (ws + 134217728);      // aliases preF (dead by then)

  // weight conversions
  k_cvt_bf16<<<dim3(8192),dim3(256),0,stream>>>(Wih,  WihB,  2*2*1024*512);
  k_cvt_fp8p<<<dim3(4096),dim3(256),0,stream>>>(Whh,  Wq8,   2*2*1024*256);
  k_cvt_bf16<<<dim3(64),  dim3(256),0,stream>>>(Wlin, WlinB, 32*512);
  k_biassum <<<dim3(16),  dim3(256),0,stream>>>(bih, bhh, bsum, 2*2*1024);

  // embedding
  k_embed<<<dim3(MROWS),dim3(64),0,stream>>>(src, emb, xA);

  for(int l=0;l<2;++l){
    const ushort_t* xin = l ? xB : xA;
    ushort_t*      xo   = l ? xA : xB;
    hipMemsetAsync(hstate, 0, 65536 + 262144, stream);
    const uchar_t*  WqL   = Wq8  + (size_t)l*2*1024*HIDDEN;
    const ushort_t* WihL  = WihB + (size_t)l*2*1024*DMODEL;
    const float*    bsumL = bsum + l*2*1024;
    for(int c=0;c<NCH;++c){
      int t0 = c*CHUNK;
      // both directions' pre-bands in one dispatch (gate-blocked N-tiles)
      k_gemm_band<<<dim3(8, 256),dim3(256),0,stream>>>(
          xin, t0, WihL, bsumL, preF, preB);
      // per-batch scan over this chunk (both directions), all 256 CUs
      k_scan3<<<dim3(256),dim3(512),0,stream>>>(
          preF, preB, WqL, hstate, cstate, xo, t0);
    }
  }

  k_logits<<<dim3(MROWS/64),dim3(256),0,stream>>>(xA, WlinB, blin, logits);
  k_crf   <<<dim3(BATCH),dim3(64),0,stream>>>(logits, trans, logz);
  k_gold  <<<dim3(BATCH),dim3(256),0,stream>>>(logits, tgt, trans, logz, partial);
  k_final <<<dim3(1),dim3(128),0,stream>>>(partial, out);
}